// Round 7
// baseline (1179.317 us; speedup 1.0000x reference)
//
#include <hip/hip_runtime.h>

typedef _Float16 f16;
typedef _Float16 f16x8 __attribute__((ext_vector_type(8)));
typedef _Float16 f16x4 __attribute__((ext_vector_type(4)));
typedef float f32x16 __attribute__((ext_vector_type(16)));

#define BS 65536
#define D 768
#define H 12
#define RB 128                   // rows per main block
#define NBLK ((BS / RB) * H)     // 6144
#define W_ELEMS ((size_t)D * D)
#define XN_ELEMS ((size_t)BS * D)
#define LNS 776                  // LN LDS row stride (8-mult -> 16B aligned reads, 4-way max)

typedef const __attribute__((address_space(1))) void gvoid_t;
typedef __attribute__((address_space(3))) void lvoid_t;

// Packed xn layout (exact MFMA A-frag order for 32x32x16):
//   elem(row, k) at  ((row>>5)*12 + (k>>6))*2048 + ((k>>4)&3)*512 + ((k>>3)&1)*256 + (row&31)*8 + (k&7)

// ---------------- prepass 1: LayerNorm -> packed xn, fully coalesced both sides ----------------
// Block = 32 rows. Phase A: wave w, row w*8+r8; lane owns f32 [lane*12,+12) (contiguous 48B/lane
// -> coalesced); stats via 6-level shfl; normalized f16 -> LDS. Phase B: repack LDS -> packed xn
// with dense 16B/lane stores (wave writes 1KB contiguous).
__global__ __launch_bounds__(256) void ln_kernel(const float* __restrict__ x,
                                                 const float* __restrict__ gamma,
                                                 const float* __restrict__ beta,
                                                 f16* __restrict__ xp) {
  __shared__ f16 sX[32][LNS];   // 48.5 KB
  const int tid = threadIdx.x;
  const int wave = tid >> 6, lane = tid & 63;
  const size_t rowbase = (size_t)blockIdx.x * 32;

  const float4* g4 = (const float4*)(gamma + lane * 12);
  const float4* b4 = (const float4*)(beta  + lane * 12);
  float4 g0 = g4[0], g1 = g4[1], g2 = g4[2];
  float4 b0 = b4[0], b1 = b4[1], b2 = b4[2];

#pragma unroll
  for (int r8 = 0; r8 < 8; ++r8) {
    const int row = wave * 8 + r8;
    const float4* xr = (const float4*)(x + (rowbase + row) * D + lane * 12);
    float4 v0 = xr[0], v1 = xr[1], v2 = xr[2];
    float sum = (v0.x + v0.y) + (v0.z + v0.w) + (v1.x + v1.y) + (v1.z + v1.w)
              + (v2.x + v2.y) + (v2.z + v2.w);
    float sq = v0.x*v0.x + v0.y*v0.y + v0.z*v0.z + v0.w*v0.w
             + v1.x*v1.x + v1.y*v1.y + v1.z*v1.z + v1.w*v1.w
             + v2.x*v2.x + v2.y*v2.y + v2.z*v2.z + v2.w*v2.w;
#pragma unroll
    for (int d2 = 1; d2 <= 32; d2 <<= 1) {
      sum += __shfl_xor(sum, d2, 64);
      sq  += __shfl_xor(sq,  d2, 64);
    }
    const float mu   = sum * (1.0f / D);
    const float rstd = rsqrtf(sq * (1.0f / D) - mu * mu + 1e-6f);
    f16* sw = &sX[row][lane * 12];
    f16x4 o;
    o[0] = (f16)((v0.x - mu) * rstd * g0.x + b0.x);
    o[1] = (f16)((v0.y - mu) * rstd * g0.y + b0.y);
    o[2] = (f16)((v0.z - mu) * rstd * g0.z + b0.z);
    o[3] = (f16)((v0.w - mu) * rstd * g0.w + b0.w);
    *(f16x4*)(sw) = o;
    o[0] = (f16)((v1.x - mu) * rstd * g1.x + b1.x);
    o[1] = (f16)((v1.y - mu) * rstd * g1.y + b1.y);
    o[2] = (f16)((v1.z - mu) * rstd * g1.z + b1.z);
    o[3] = (f16)((v1.w - mu) * rstd * g1.w + b1.w);
    *(f16x4*)(sw + 4) = o;
    o[0] = (f16)((v2.x - mu) * rstd * g2.x + b2.x);
    o[1] = (f16)((v2.y - mu) * rstd * g2.y + b2.y);
    o[2] = (f16)((v2.z - mu) * rstd * g2.z + b2.z);
    o[3] = (f16)((v2.w - mu) * rstd * g2.w + b2.w);
    *(f16x4*)(sw + 8) = o;
  }
  __syncthreads();
  // Phase B: packed region for this 32-row group = contiguous 24576 f16
  f16* base = xp + (size_t)blockIdx.x * 24576;
  const int s    = (tid >> 6) & 3;
  const int half = (tid >> 5) & 1;
  const int row  = tid & 31;
#pragma unroll
  for (int i = 0; i < 12; ++i) {
    const int k = i * 64 + s * 16 + half * 8;
    f16x8 v = *(const f16x8*)(&sX[row][k]);
    *(f16x8*)(base + i * 2048 + tid * 8) = v;
  }
}

// ---------------- prepass 2: W f32 -> f16 ----------------
__global__ __launch_bounds__(256, 4) void wconv_kernel(const float* __restrict__ Wq,
                                                       const float* __restrict__ Wk,
                                                       const float* __restrict__ Wv,
                                                       f16* __restrict__ wf) {
  int b = blockIdx.x;          // 0..863 (3 * 288)
  int m = b / 288;
  size_t e = ((size_t)(b % 288) * 256 + threadIdx.x) * 8;
  const float* src = (m == 0 ? Wq : (m == 1 ? Wk : Wv)) + e;
  float4 v0 = *(const float4*)src;
  float4 v1 = *(const float4*)(src + 4);
  f16x8 o;
  o[0] = (f16)v0.x; o[1] = (f16)v0.y; o[2] = (f16)v0.z; o[3] = (f16)v0.w;
  o[4] = (f16)v1.x; o[5] = (f16)v1.y; o[6] = (f16)v1.z; o[7] = (f16)v1.w;
  *(f16x8*)(wf + (size_t)m * W_ELEMS + e) = o;
}

// ---------------- main: QKV GEMM (32x32x16) + 2x2 attention + residual ----------------
// 128 rows x 192 cols per block, 4 waves. COLUMN-SPLIT: wave (wr,wc) owns 64 rows x 3 col-tiles:
//   wc=0: {q_p0(T0), k_p0(T2), k_p1(T3)}   wc=1: {q_p1(T1), v_p0(T4), v_p1(T5)}
// -> each B-frag ds_read feeds 2 MFMAs (rt=0,1): B LDS reads per wave per K-step 24 -> 12,
// dropping LDS-read demand below the 128B/cyc pipe so MFMA can win. Same 6 accs / regs /
// occupancy (3 blocks/CU). Epilogue: wc=0 computes s00,s01, shares k0,k1 (f16) + s via dead
// sB[0]; wc=1 computes s10,s11, softmax, output (it holds v).
__global__ __launch_bounds__(256, 3) void qkv_attn_kernel(const f16* __restrict__ xp,
                                                          const f16* __restrict__ wf,
                                                          const float* __restrict__ x,
                                                          float* __restrict__ out) {
  __shared__ f16 sB[2][192 * 64] __attribute__((aligned(16)));   // 48 KB

  const int tid  = threadIdx.x;
  const int wave = tid >> 6;
  const int lane = tid & 63;
  const int l31  = lane & 31;
  const int hi   = lane >> 5;
  const int wr   = wave >> 1;   // row-group: rows wr*64
  const int wc   = wave & 1;    // col-group

  // XCD-bijective swizzle: 12 head-blocks of one rb land on the same XCD (xn L2 reuse)
  int bid = blockIdx.x;
  int my  = (bid & 7) * (NBLK / 8) + (bid >> 3);
  int rb  = my / H;
  int h   = my % H;

  const int ri = lane >> 3;   // staging row-in-op
  const int ci = lane & 7;    // staging LDS slot -> global chunk ci ^ ri

  // B staging (all 4 waves cover the shared 192x64 tile): 6 ops/wave
  unsigned boffs[6];
#pragma unroll
  for (int o = 0; o < 6; ++o) {
    int n = wave * 48 + o * 8 + ri;
    boffs[o] = (unsigned)((n >> 6) * (int)W_ELEMS + (h * 64 + (n & 63)) * D + ((ci ^ ri) * 8));
  }

  // B-frag read offsets (content swizzle: chunk kc at slot kc ^ (row&7))
  const int q7 = l31 & 7;
  int coff[4];
#pragma unroll
  for (int s = 0; s < 4; ++s) coff[s] = l31 * 64 + (((s * 2 + hi) ^ q7) * 8);
  const int tb0 = (wc ? 1 : 0) * 2048;   // tile bases (f16 elems)
  const int tb1 = (wc ? 4 : 2) * 2048;
  const int tb2 = (wc ? 5 : 3) * 2048;

  // A in packed xn: row-groups rb*4 + wr*2 + rt
  const f16* ap0 = xp + ((size_t)(rb * 4 + wr * 2) * 12) * 2048 + hi * 256 + l31 * 8;
  const f16* ap1 = ap0 + 12 * 2048;

#define STAGE(KO, BUF)                                                                   \
  {                                                                                      \
    _Pragma("unroll") for (int o = 0; o < 6; ++o) {                                      \
      __builtin_amdgcn_global_load_lds((gvoid_t*)(wf + boffs[o] + (KO) * 64),            \
                                       (lvoid_t*)(&sB[BUF][(wave * 48 + o * 8) * 64]),   \
                                       16, 0, 0);                                        \
    }                                                                                    \
  }

  STAGE(0, 0);

  f32x16 acc[3][2];
#pragma unroll
  for (int t = 0; t < 3; ++t)
#pragma unroll
    for (int rt = 0; rt < 2; ++rt)
#pragma unroll
      for (int i = 0; i < 16; ++i) acc[t][rt][i] = 0.f;

#pragma unroll
  for (int ko = 0; ko < 12; ++ko) {
    const int cur = ko & 1;

    // 1) this step's A-frags: 8 coalesced 1024B wave-loads (2 row-groups x 4 k-slices)
    f16x8 a0[4], a1[4];
#pragma unroll
    for (int s = 0; s < 4; ++s) {
      a0[s] = *(const f16x8*)(ap0 + ko * 2048 + s * 512);
      a1[s] = *(const f16x8*)(ap1 + ko * 2048 + s * 512);
    }
    __builtin_amdgcn_sched_barrier(0);
    // 2) next tile's staging (6 ops -> buf cur^1)
    if (ko < 11) STAGE(ko + 1, cur ^ 1);
    __builtin_amdgcn_sched_barrier(0);
    // 3) drain stage(ko) only: outstanding = stage(ko)[6] + A[8] + stage(ko+1)[6]
    if (ko < 11) asm volatile("s_waitcnt vmcnt(14)" ::: "memory");
    else         asm volatile("s_waitcnt vmcnt(8)" ::: "memory");
    __builtin_amdgcn_sched_barrier(0);
    __builtin_amdgcn_s_barrier();

    __builtin_amdgcn_s_setprio(1);
#pragma unroll
    for (int s = 0; s < 4; ++s) {
      f16x8 b0 = *(const f16x8*)(&sB[cur][tb0 + coff[s]]);
      f16x8 b1 = *(const f16x8*)(&sB[cur][tb1 + coff[s]]);
      f16x8 b2 = *(const f16x8*)(&sB[cur][tb2 + coff[s]]);
      acc[0][0] = __builtin_amdgcn_mfma_f32_32x32x16_f16(a0[s], b0, acc[0][0], 0, 0, 0);
      acc[0][1] = __builtin_amdgcn_mfma_f32_32x32x16_f16(a1[s], b0, acc[0][1], 0, 0, 0);
      acc[1][0] = __builtin_amdgcn_mfma_f32_32x32x16_f16(a0[s], b1, acc[1][0], 0, 0, 0);
      acc[1][1] = __builtin_amdgcn_mfma_f32_32x32x16_f16(a1[s], b1, acc[1][1], 0, 0, 0);
      acc[2][0] = __builtin_amdgcn_mfma_f32_32x32x16_f16(a0[s], b2, acc[2][0], 0, 0, 0);
      acc[2][1] = __builtin_amdgcn_mfma_f32_32x32x16_f16(a1[s], b2, acc[2][1], 0, 0, 0);
    }
    __builtin_amdgcn_s_setprio(0);

    if (ko < 11) {
      asm volatile("s_waitcnt lgkmcnt(0)" ::: "memory");
      __builtin_amdgcn_sched_barrier(0);
      __builtin_amdgcn_s_barrier();
    }
  }

  // ---- epilogue: cross-wave 2x2 attention ----
  // C/D layout: col-in-tile = l31, row-in-tile = (g&3) + 8*(g>>2) + 4*hi
  f16*   sK0 = &sB[0][0];                    // [128 rows][32 dk] f16  (8 KB)
  f16*   sK1 = &sB[0][4096];                 // 8 KB
  float* sS  = (float*)&sB[0][8192];         // [128][2] f32 (1 KB)  -- all within dead sB[0]
  const float scale = 0.17677669529663687f;  // 1/sqrt(32)

  if (wc == 0) {
#pragma unroll
    for (int rt = 0; rt < 2; ++rt) {
#pragma unroll
      for (int g = 0; g < 16; ++g) {
        const int row = wr * 64 + rt * 32 + (g & 3) + 8 * (g >> 2) + 4 * hi;
        float q0 = acc[0][rt][g], k0 = acc[1][rt][g], k1 = acc[2][rt][g];
        float t00 = q0 * k0, t01 = q0 * k1;
#pragma unroll
        for (int d2 = 1; d2 <= 16; d2 <<= 1) {
          t00 += __shfl_xor(t00, d2, 64);
          t01 += __shfl_xor(t01, d2, 64);
        }
        sK0[row * 32 + l31] = (f16)k0;
        sK1[row * 32 + l31] = (f16)k1;
        if (l31 == 0) { sS[row * 2] = t00 * scale; sS[row * 2 + 1] = t01 * scale; }
      }
    }
  }
  __syncthreads();
  if (wc == 1) {
#pragma unroll
    for (int rt = 0; rt < 2; ++rt) {
#pragma unroll
      for (int g = 0; g < 16; ++g) {
        const int row = wr * 64 + rt * 32 + (g & 3) + 8 * (g >> 2) + 4 * hi;
        float q1 = acc[0][rt][g];
        float k0 = (float)sK0[row * 32 + l31];
        float k1 = (float)sK1[row * 32 + l31];
        float t10 = q1 * k0, t11 = q1 * k1;
#pragma unroll
        for (int d2 = 1; d2 <= 16; d2 <<= 1) {
          t10 += __shfl_xor(t10, d2, 64);
          t11 += __shfl_xor(t11, d2, 64);
        }
        float s00 = sS[row * 2], s01 = sS[row * 2 + 1];
        float s10 = t10 * scale, s11 = t11 * scale;
        float mx0 = fmaxf(s00, s01);
        float e00 = __expf(s00 - mx0), e01 = __expf(s01 - mx0);
        float r0 = 1.0f / (e00 + e01);
        float a00 = e00 * r0, a01 = e01 * r0;
        float mx1 = fmaxf(s10, s11);
        float e10 = __expf(s10 - mx1), e11 = __expf(s11 - mx1);
        float r1 = 1.0f / (e10 + e11);
        float a10 = e10 * r1, a11 = e11 * r1;

        float v0 = acc[1][rt][g], v1 = acc[2][rt][g];
        const size_t grow = (size_t)rb * RB + row;
        const float* xq = x   + grow * D + h * 64 + l31;
        float*       op = out + grow * D + h * 64 + l31;
        op[0]  = a00 * v0 + a01 * v1 + xq[0];    // p0: col h*64 + dk
        op[32] = a10 * v0 + a11 * v1 + xq[32];   // p1: col h*64 + 32 + dk
      }
    }
  }
#undef STAGE
}

extern "C" void kernel_launch(void* const* d_in, const int* in_sizes, int n_in,
                              void* d_out, int out_size, void* d_ws, size_t ws_size,
                              hipStream_t stream) {
  const float* x     = (const float*)d_in[0];
  const float* Wq    = (const float*)d_in[1];
  const float* Wk    = (const float*)d_in[2];
  const float* Wv    = (const float*)d_in[3];
  const float* gamma = (const float*)d_in[4];
  const float* beta  = (const float*)d_in[5];
  float* out = (float*)d_out;
  (void)in_sizes; (void)n_in; (void)out_size; (void)ws_size;

  f16* xp = (f16*)d_ws;                 // 100.7 MB (packed xn)
  f16* wf = xp + XN_ELEMS;              // + 3.5 MB  (needs ws_size >= ~104.3 MB)

  ln_kernel<<<dim3(BS / 32), dim3(256), 0, stream>>>(x, gamma, beta, xp);
  wconv_kernel<<<dim3(864), dim3(256), 0, stream>>>(Wq, Wk, Wv, wf);
  qkv_attn_kernel<<<dim3(NBLK), dim3(256), 0, stream>>>(xp, wf, x, out);
}